// Round 5
// baseline (676.015 us; speedup 1.0000x reference)
//
#include <hip/hip_runtime.h>
#include <math.h>

#define NSEQ 2048
#define NFFT 4096
#define D1C  1536
#define EMBC 512
#define BATCH 4

typedef __fp16 f16;
typedef __fp16 f16x8 __attribute__((ext_vector_type(8)));
typedef __fp16 f16x4 __attribute__((ext_vector_type(4)));
typedef float  f32x4 __attribute__((ext_vector_type(4)));
typedef unsigned int u32;

__device__ __forceinline__ float silu_f(float y) { return y / (1.f + expf(-y)); }

// ---------------------------------------------------------------------------
// row-norm scale: scale[row] = 1/(||x_row|| * D1^-0.5 + 1e-8)
__global__ __launch_bounds__(256) void scale_kernel(const float* __restrict__ x,
                                                    float* __restrict__ scale) {
    int row  = blockIdx.x * 4 + (threadIdx.x >> 6);
    int lane = threadIdx.x & 63;
    const float* xr = x + (size_t)row * EMBC;
    float ss = 0.f;
#pragma unroll
    for (int k = 0; k < EMBC / 64; ++k) { float v = xr[lane + k * 64]; ss += v * v; }
#pragma unroll
    for (int off = 32; off >= 1; off >>= 1) ss += __shfl_xor(ss, off);
    if (lane == 0) scale[row] = 1.f / (sqrtf(ss) * 0.02551551815399144f + 1e-8f);
}

// xn = x * scale  -> f16 hi/lo
__global__ __launch_bounds__(256) void convert_xn_kernel(
    const float* __restrict__ x, const float* __restrict__ scale,
    f16* __restrict__ xh, f16* __restrict__ xl) {
    size_t i = ((size_t)blockIdx.x * 256 + threadIdx.x) * 4;
    float4 v = *reinterpret_cast<const float4*>(x + i);
    float s = scale[i >> 9];
    f16x4 h, l;
    const float* vv = (const float*)&v;
#pragma unroll
    for (int j = 0; j < 4; ++j) {
        float val = vv[j] * s;
        f16 hh = (f16)val;
        h[j] = hh; l[j] = (f16)(val - (float)hh);
    }
    *reinterpret_cast<f16x4*>(xh + i) = h;
    *reinterpret_cast<f16x4*>(xl + i) = l;
}

// x2 = a + b -> f16 hi/lo
__global__ __launch_bounds__(256) void convert_x2_kernel(
    const float* __restrict__ a, const float* __restrict__ b,
    f16* __restrict__ xh, f16* __restrict__ xl) {
    size_t i = ((size_t)blockIdx.x * 256 + threadIdx.x) * 4;
    float4 va = *reinterpret_cast<const float4*>(a + i);
    float4 vb = *reinterpret_cast<const float4*>(b + i);
    const float* pa = (const float*)&va;
    const float* pb = (const float*)&vb;
    f16x4 h, l;
#pragma unroll
    for (int j = 0; j < 4; ++j) {
        float val = pa[j] + pb[j];
        f16 hh = (f16)val;
        h[j] = hh; l[j] = (f16)(val - (float)hh);
    }
    *reinterpret_cast<f16x4*>(xh + i) = h;
    *reinterpret_cast<f16x4*>(xl + i) = l;
}

// W[K][N] fp32 -> WT[N][K] f16 hi only (LDS tile transpose)
__global__ __launch_bounds__(256) void wtrans_kernel(const float* __restrict__ W,
        f16* __restrict__ Th, int Kd, int Nd) {
    __shared__ float t[32][33];
    int tx = threadIdx.x & 31, ty = threadIdx.x >> 5;
    int n0 = blockIdx.x * 32, k0 = blockIdx.y * 32;
#pragma unroll
    for (int yy = ty; yy < 32; yy += 8)
        t[yy][tx] = W[(size_t)(k0 + yy) * Nd + n0 + tx];
    __syncthreads();
#pragma unroll
    for (int yy = ty; yy < 32; yy += 8) {
        float v = t[tx][yy];
        Th[(size_t)(n0 + yy) * Kd + k0 + tx] = (f16)v;
    }
}

// p = u * t (vt layout [b][col][n]) -> f16 hi/lo row-major [8192][1536]
__global__ __launch_bounds__(256) void convert_p_kernel(
    const float* __restrict__ u, const float* __restrict__ vt,
    f16* __restrict__ ph, f16* __restrict__ pl) {
    __shared__ float t[32][33];
    int b = blockIdx.z, n0 = blockIdx.x * 32, c0 = blockIdx.y * 32;
    int tx = threadIdx.x & 31, ty = threadIdx.x >> 5;
#pragma unroll
    for (int yy = ty; yy < 32; yy += 8)
        t[yy][tx] = vt[(((size_t)(b * D1C + c0 + yy)) << 11) + n0 + tx];
    __syncthreads();
#pragma unroll
    for (int yy = ty; yy < 32; yy += 8) {
        int row = b * NSEQ + n0 + yy;
        size_t idx = (size_t)row * D1C + c0 + tx;
        float val = u[idx] * t[tx][yy];
        f16 h = (f16)val;
        ph[idx] = h; pl[idx] = (f16)(val - (float)h);
    }
}

// ---------------------------------------------------------------------------
// RPE MLP: 4096 positions -> a_r[col][pos] (real), col = h*HD+d
__global__ __launch_bounds__(256) void rpe_kernel(
    const float* __restrict__ pw, const float* __restrict__ pb,
    const float* __restrict__ lw, const float* __restrict__ lb,
    const float* __restrict__ ow, const float* __restrict__ ob,
    float* __restrict__ a_r) {
    __shared__ float hs[64][33];
    int tid = threadIdx.x;
    int s0  = blockIdx.x * 64;
    if (tid < 64) {
        int s = s0 + tid;
        float p = (s == 0 || s == 2048) ? 0.f : (s < 2048 ? (float)s : (float)(s - 4096));
        float h[32];
#pragma unroll
        for (int k = 0; k < 32; ++k) h[k] = fmaxf(p * pw[k] + pb[k], 0.f);
        for (int L = 0; L < 3; ++L) {
            float ss = 0.f;
#pragma unroll
            for (int k = 0; k < 32; ++k) ss += h[k] * h[k];
            float sc = 1.f / (sqrtf(ss) * 0.1767766952966369f + 1e-8f);
            float g[32];
#pragma unroll
            for (int k = 0; k < 32; ++k) g[k] = fmaxf(h[k] * sc, 0.f);
#pragma unroll
            for (int j = 0; j < 32; ++j) {
                float acc = lb[L * 32 + j];
#pragma unroll
                for (int k = 0; k < 32; ++k) acc += g[k] * lw[(L * 32 + k) * 32 + j];
                h[j] = acc;
            }
        }
        float ss = 0.f;
#pragma unroll
        for (int k = 0; k < 32; ++k) ss += h[k] * h[k];
        float sc = 1.f / (sqrtf(ss) * 0.1767766952966369f + 1e-8f);
#pragma unroll
        for (int k = 0; k < 32; ++k) hs[tid][k] = fmaxf(h[k] * sc, 0.f);
    }
    __syncthreads();
    for (int cc = 0; cc < 6; ++cc) {
        int col = tid + cc * 256;
        float wcol[32];
#pragma unroll
        for (int k = 0; k < 32; ++k) wcol[k] = ow[k * D1C + col];
        float bb = ob[col];
        float* outp = a_r + ((size_t)col << 12) + s0;
        for (int r = 0; r < 64; ++r) {
            float acc = bb;
#pragma unroll
            for (int k = 0; k < 32; ++k) acc += hs[r][k] * wcol[k];
            outp[r] = acc;
        }
    }
}

// ---------------------------------------------------------------------------
// radix-16 register FFT, 4096 = 16^3, 256 threads, 16 pts/thread.
// Storage enumeration e = a*256 + b*16 + c; LDS pad phi(e) = e + 2*(e>>4).
// Spectrum stored/consumed at chi(q) = (q&15)*256 + (q>>4)  (q = k0*256+k1*16+k2).
#define LIDX(e) ((e) + ((((e) >> 4)) << 1))

// 16-point DFT: out[k] = sum_n in[n] * W16^{+-nk}  (INV: +, fwd: -)
// HALF: inputs n=8..15 are zero (not read).
template <bool INV, bool HALF>
__device__ __forceinline__ void dft16(const float* xr, const float* xi,
                                      float* outr, float* outi) {
    constexpr float C1 = 0.92387953251f, S1 = 0.38268343236f, R2 = 0.70710678119f;
    constexpr float sg = INV ? 1.f : -1.f;
    float tr[16], ti[16];
    // layer 1: radix-4 over m = n>>2 (stride 4); y_j(n0) -> t[n0+4j], * W16^{j*n0}
#pragma unroll
    for (int n0 = 0; n0 < 4; ++n0) {
        float ar = xr[n0], ai = xi[n0];
        float br = xr[n0 + 4], bi = xi[n0 + 4];
        float j0r, j0i, j1r, j1i, j2r, j2i, j3r, j3i;
        if constexpr (HALF) {
            j0r = ar + br; j0i = ai + bi;
            j2r = ar - br; j2i = ai - bi;
            if constexpr (!INV) { j1r = ar + bi; j1i = ai - br; j3r = ar - bi; j3i = ai + br; }
            else                { j1r = ar - bi; j1i = ai + br; j3r = ar + bi; j3i = ai - br; }
        } else {
            float cr = xr[n0 + 8],  ci = xi[n0 + 8];
            float dr = xr[n0 + 12], di = xi[n0 + 12];
            float t0r = ar + cr, t0i = ai + ci;
            float t1r = ar - cr, t1i = ai - ci;
            float t2r = br + dr, t2i = bi + di;
            float t3r = br - dr, t3i = bi - di;
            j0r = t0r + t2r; j0i = t0i + t2i;
            j2r = t0r - t2r; j2i = t0i - t2i;
            if constexpr (!INV) { j1r = t1r + t3i; j1i = t1i - t3r;
                                  j3r = t1r - t3i; j3i = t1i + t3r; }
            else                { j1r = t1r - t3i; j1i = t1i + t3r;
                                  j3r = t1r + t3i; j3i = t1i - t3r; }
        }
        tr[n0] = j0r;      ti[n0] = j0i;
        tr[n0 + 4] = j1r;  ti[n0 + 4] = j1i;
        tr[n0 + 8] = j2r;  ti[n0 + 8] = j2i;
        tr[n0 + 12] = j3r; ti[n0 + 12] = j3i;
    }
    // internal twiddles W16^{j*n0} at t[n0+4j], (j,n0) nonzero
#define CMK(idx, wr_, wi_) { float _r = tr[idx], _i = ti[idx]; \
        tr[idx] = _r * (wr_) - _i * (wi_); ti[idx] = _r * (wi_) + _i * (wr_); }
    CMK(5,  C1, sg * S1)  CMK(6,  R2, sg * R2)  CMK(7,  S1, sg * C1)
    CMK(9,  R2, sg * R2)
    { float _r = tr[10];
      if constexpr (!INV) { tr[10] = ti[10];  ti[10] = -_r; }
      else                { tr[10] = -ti[10]; ti[10] = _r;  } }
    CMK(11, -R2, sg * R2)
    CMK(13, S1, sg * C1)  CMK(14, -R2, sg * R2)  CMK(15, -C1, -sg * S1)
#undef CMK
    // layer 2: radix-4 over n0 (contiguous quads); out[4t + j]
#pragma unroll
    for (int j = 0; j < 4; ++j) {
        float ar = tr[4 * j],     ai = ti[4 * j];
        float br = tr[4 * j + 1], bi = ti[4 * j + 1];
        float cr = tr[4 * j + 2], ci = ti[4 * j + 2];
        float dr = tr[4 * j + 3], di = ti[4 * j + 3];
        float t0r = ar + cr, t0i = ai + ci;
        float t1r = ar - cr, t1i = ai - ci;
        float t2r = br + dr, t2i = bi + di;
        float t3r = br - dr, t3i = bi - di;
        outr[j]      = t0r + t2r; outi[j]      = t0i + t2i;
        outr[8 + j]  = t0r - t2r; outi[8 + j]  = t0i - t2i;
        if constexpr (!INV) {
            outr[4 + j]  = t1r + t3i; outi[4 + j]  = t1i - t3r;
            outr[12 + j] = t1r - t3i; outi[12 + j] = t1i + t3r;
        } else {
            outr[4 + j]  = t1r - t3i; outi[4 + j]  = t1i + t3r;
            outr[12 + j] = t1r + t3i; outi[12 + j] = t1i - t3r;
        }
    }
}

#define CMUL_ADV(wr, wi, sr, si) { float _n = (wr)*(sr) - (wi)*(si); \
        (wi) = (wr)*(si) + (wi)*(sr); (wr) = _n; }

// forward-FFT the (real) RPE rows -> af at chi-order (coalesced stores)
__global__ __launch_bounds__(256, 4) void fft_a_kernel(const float* __restrict__ a_r,
                                                       float2* __restrict__ af) {
    __shared__ float2 buf[4608];
    int tid = threadIdx.x;
    const float* row = a_r + ((size_t)blockIdx.x << 12);
    float2* orow     = af  + ((size_t)blockIdx.x << 12);
    float xr[16], xi[16], yr[16], yi[16];
    float bsr, bsi, wr, wi;
    // stage 1: a-axis (stride 256)
#pragma unroll
    for (int a = 0; a < 16; ++a) { xr[a] = row[a * 256 + tid]; xi[a] = 0.f; }
    dft16<false, false>(xr, xi, yr, yi);
    __sincosf(-(float)M_PI / 2048.f * (float)tid, &bsi, &bsr);
    wr = bsr; wi = bsi;
    buf[LIDX(tid)] = make_float2(yr[0], yi[0]);
#pragma unroll
    for (int k0 = 1; k0 < 16; ++k0) {
        buf[LIDX(k0 * 256 + tid)] =
            make_float2(yr[k0] * wr - yi[k0] * wi, yr[k0] * wi + yi[k0] * wr);
        CMUL_ADV(wr, wi, bsr, bsi);
    }
    __syncthreads();
    // stage 2: b-axis (stride 16)
    int k0 = tid >> 4, cc = tid & 15;
    int base2 = k0 * 256 + cc;
#pragma unroll
    for (int b = 0; b < 16; ++b) {
        float2 v = buf[LIDX(base2 + b * 16)]; xr[b] = v.x; xi[b] = v.y;
    }
    dft16<false, false>(xr, xi, yr, yi);
    __sincosf(-(float)M_PI / 128.f * (float)cc, &bsi, &bsr);
    wr = bsr; wi = bsi;
    buf[LIDX(base2)] = make_float2(yr[0], yi[0]);
#pragma unroll
    for (int k1 = 1; k1 < 16; ++k1) {
        buf[LIDX(base2 + k1 * 16)] =
            make_float2(yr[k1] * wr - yi[k1] * wi, yr[k1] * wi + yi[k1] * wr);
        CMUL_ADV(wr, wi, bsr, bsi);
    }
    __syncthreads();
    // stage 3: c-axis (contiguous, b128 loads), store chi-transposed
    const float4* pld = (const float4*)&buf[18 * tid];
#pragma unroll
    for (int h = 0; h < 8; ++h) {
        float4 q = pld[h];
        xr[2 * h] = q.x; xi[2 * h] = q.y; xr[2 * h + 1] = q.z; xi[2 * h + 1] = q.w;
    }
    dft16<false, false>(xr, xi, yr, yi);
#pragma unroll
    for (int k2 = 0; k2 < 16; ++k2)
        orow[k2 * 256 + tid] = make_float2(yr[k2], yi[k2]);
}

// packed circular convolution: z = v[b0] + i*v[b1]; fwd FFT -> *af -> inv FFT
__global__ __launch_bounds__(256, 4) void conv_kernel(float* __restrict__ vt,
                                                      const float2* __restrict__ af) {
    __shared__ float2 buf[4608];
    int tid = threadIdx.x;
    int pr  = blockIdx.x / D1C;
    int col = blockIdx.x % D1C;
    float* v0 = vt + ((size_t)((2 * pr)     * D1C + col) << 11);
    float* v1 = vt + ((size_t)((2 * pr + 1) * D1C + col) << 11);
    const float2* arow = af + ((size_t)col << 12);
    float xr[16], xi[16], yr[16], yi[16];
    float bsr, bsi, wr, wi;

    // ---- fwd stage 1 (a-axis), upper half zero
#pragma unroll
    for (int a = 0; a < 8; ++a) { xr[a] = v0[a * 256 + tid]; xi[a] = v1[a * 256 + tid]; }
    dft16<false, true>(xr, xi, yr, yi);
    __sincosf(-(float)M_PI / 2048.f * (float)tid, &bsi, &bsr);
    wr = bsr; wi = bsi;
    buf[LIDX(tid)] = make_float2(yr[0], yi[0]);
#pragma unroll
    for (int k0 = 1; k0 < 16; ++k0) {
        buf[LIDX(k0 * 256 + tid)] =
            make_float2(yr[k0] * wr - yi[k0] * wi, yr[k0] * wi + yi[k0] * wr);
        CMUL_ADV(wr, wi, bsr, bsi);
    }
    __syncthreads();
    // ---- fwd stage 2 (b-axis)
    int k0 = tid >> 4, cc = tid & 15;
    int base2 = k0 * 256 + cc;
#pragma unroll
    for (int b = 0; b < 16; ++b) {
        float2 v = buf[LIDX(base2 + b * 16)]; xr[b] = v.x; xi[b] = v.y;
    }
    dft16<false, false>(xr, xi, yr, yi);
    __sincosf(-(float)M_PI / 128.f * (float)cc, &bsi, &bsr);
    wr = bsr; wi = bsi;
    buf[LIDX(base2)] = make_float2(yr[0], yi[0]);
#pragma unroll
    for (int k1 = 1; k1 < 16; ++k1) {
        buf[LIDX(base2 + k1 * 16)] =
            make_float2(yr[k1] * wr - yi[k1] * wi, yr[k1] * wi + yi[k1] * wr);
        CMUL_ADV(wr, wi, bsr, bsi);
    }
    __syncthreads();
    // ---- fwd stage 3 (c-axis, registers) + pointwise + inv stage A (fused)
    const float4* pld = (const float4*)&buf[18 * tid];
#pragma unroll
    for (int h = 0; h < 8; ++h) {
        float4 q = pld[h];
        xr[2 * h] = q.x; xi[2 * h] = q.y; xr[2 * h + 1] = q.z; xi[2 * h + 1] = q.w;
    }
    dft16<false, false>(xr, xi, yr, yi);
    const float inv = 1.0f / 4096.0f;
#pragma unroll
    for (int k2 = 0; k2 < 16; ++k2) {
        float2 w = arow[k2 * 256 + tid];
        float rr = (yr[k2] * w.x - yi[k2] * w.y) * inv;
        float ii = (yr[k2] * w.y + yi[k2] * w.x) * inv;
        xr[k2] = rr; xi[k2] = ii;
    }
    dft16<true, false>(xr, xi, yr, yi);           // IDFT over k2 -> c
    __sincosf((float)M_PI / 128.f * (float)cc, &bsi, &bsr);  // conj(T2) base W^{+16*k1}
    // NOTE: thread here is (k0, k1) with k1 = tid&15 == cc
    wr = bsr; wi = bsi;
#pragma unroll
    for (int c = 1; c < 16; ++c) {
        float rr = yr[c] * wr - yi[c] * wi;
        yi[c] = yr[c] * wi + yi[c] * wr; yr[c] = rr;
        CMUL_ADV(wr, wi, bsr, bsi);
    }
    float4* pst = (float4*)&buf[18 * tid];
#pragma unroll
    for (int h = 0; h < 8; ++h)
        pst[h] = make_float4(yr[2 * h], yi[2 * h], yr[2 * h + 1], yi[2 * h + 1]);
    __syncthreads();
    // ---- inv stage B (k1-axis -> b), * W^{+k0(16b+c)}
#pragma unroll
    for (int k1 = 0; k1 < 16; ++k1) {
        float2 v = buf[LIDX(base2 + k1 * 16)]; xr[k1] = v.x; xi[k1] = v.y;
    }
    dft16<true, false>(xr, xi, yr, yi);
    float swr, swi;
    __sincosf((float)M_PI / 2048.f * (float)(k0 * cc), &bsi, &bsr);  // W^{+k0*c}
    __sincosf((float)M_PI / 128.f * (float)k0, &swi, &swr);          // W^{+16*k0}
    wr = bsr; wi = bsi;
#pragma unroll
    for (int b = 0; b < 16; ++b) {
        buf[LIDX(base2 + b * 16)] =
            make_float2(yr[b] * wr - yi[b] * wi, yr[b] * wi + yi[b] * wr);
        CMUL_ADV(wr, wi, swr, swi);
    }
    __syncthreads();
    // ---- inv stage C (k0-axis -> a), store first half
#pragma unroll
    for (int k = 0; k < 16; ++k) {
        float2 v = buf[LIDX(k * 256 + tid)]; xr[k] = v.x; xi[k] = v.y;
    }
    dft16<true, false>(xr, xi, yr, yi);
#pragma unroll
    for (int a = 0; a < 8; ++a) {
        v0[a * 256 + tid] = yr[a];
        v1[a * 256 + tid] = yi[a];
    }
}

// ---------------------------------------------------------------------------
// MFMA 2-pass split-f16 GEMM: C = (Ah+Al)*Bh, fp32 accum (B rounded to f16).
enum { EP_SILU_F32, EP_SILU_VT, EP_PLAIN, EP_GLU2 };

template <int BM, int K, int EPI>
__global__ __launch_bounds__(256, (BM == 128 ? 3 : 4)) void mgemm(
    const f16* __restrict__ Ah, const f16* __restrict__ Al,
    const f16* __restrict__ Bh,
    const float* __restrict__ bias, const float* __restrict__ E0,
    float* __restrict__ OutF, f16* __restrict__ OutH, f16* __restrict__ OutL,
    int Ncols) {
    constexpr int SB   = BM * 128 + 8192;
    constexpr int MREP = BM / 32;
    constexpr int LOGB = (BM == 128 ? 7 : 6);
    constexpr int CA   = BM / 64;
    __shared__ __align__(16) char smem[2 * SB];

    const int tid  = threadIdx.x;
    const int w    = tid >> 6, lane = tid & 63;
    const int wr   = w >> 1, wc = w & 1;
    const int l15  = lane & 15, kc = lane >> 4;

    const int NBY = Ncols >> 7;
    const int nwg = gridDim.x;
    int flat = blockIdx.x;
    int q8 = nwg >> 3, r8 = nwg & 7;
    int xcd = flat & 7, pos = flat >> 3;
    int wg = (xcd < r8 ? xcd * (q8 + 1) : r8 * (q8 + 1) + (xcd - r8) * q8) + pos;
    const int row0 = (wg / NBY) * BM;
    const int col0 = (wg % NBY) * 128;

    f32x4 acc[MREP][4] = {};

    auto stage = [&](int buf, int kt) {
        const int k0 = kt * 32;
        const int bb = buf * SB;
#pragma unroll
        for (int l = 0; l < CA; ++l) {
            int ci = tid + l * 256;
            int r = ci & (BM - 1), kk = ci >> LOGB;
            const f16* ga = Ah + (size_t)(row0 + r) * K + k0 + kk * 8;
            const f16* gb = Al + (size_t)(row0 + r) * K + k0 + kk * 8;
            __builtin_amdgcn_global_load_lds((const __attribute__((address_space(1))) u32*)ga,
                (__attribute__((address_space(3))) u32*)(smem + bb + ci * 16), 16, 0, 0);
            __builtin_amdgcn_global_load_lds((const __attribute__((address_space(1))) u32*)gb,
                (__attribute__((address_space(3))) u32*)(smem + bb + BM * 64 + ci * 16), 16, 0, 0);
        }
#pragma unroll
        for (int l = 0; l < 2; ++l) {
            int ci = tid + l * 256;
            int c = ci & 127, kk = ci >> 7;
            const f16* gc = Bh + (size_t)(col0 + c) * K + k0 + kk * 8;
            __builtin_amdgcn_global_load_lds((const __attribute__((address_space(1))) u32*)gc,
                (__attribute__((address_space(3))) u32*)(smem + bb + BM * 128 + ci * 16), 16, 0, 0);
        }
    };

    auto compute = [&](int buf) {
        const char* base = smem + buf * SB;
        f16x8 a_h[MREP], a_l[MREP], b_h[4];
#pragma unroll
        for (int m = 0; m < MREP; ++m) {
            int r = wr * (BM / 2) + m * 16 + l15;
            a_h[m] = *(const f16x8*)(base + (kc * BM + r) * 16);
            a_l[m] = *(const f16x8*)(base + BM * 64 + (kc * BM + r) * 16);
        }
#pragma unroll
        for (int n = 0; n < 4; ++n) {
            int c = wc * 64 + n * 16 + l15;
            b_h[n] = *(const f16x8*)(base + BM * 128 + (kc * 128 + c) * 16);
        }
#pragma unroll
        for (int m = 0; m < MREP; ++m)
#pragma unroll
            for (int n = 0; n < 4; ++n) {
                acc[m][n] = __builtin_amdgcn_mfma_f32_16x16x32_f16(a_h[m], b_h[n], acc[m][n], 0, 0, 0);
                acc[m][n] = __builtin_amdgcn_mfma_f32_16x16x32_f16(a_l[m], b_h[n], acc[m][n], 0, 0, 0);
            }
    };

    constexpr int NT = K / 32;
    stage(0, 0);
    __syncthreads();
    int cur = 0;
    for (int t = 0; t < NT; ++t) {
        if (t + 1 < NT) stage(cur ^ 1, t + 1);
        compute(cur);
        __syncthreads();
        cur ^= 1;
    }

    const int WRB = wr * (BM / 2);
    if constexpr (EPI == EP_SILU_VT) {
        float* patch = (float*)(smem + w * 5376);        // [64][20] f32, padded
#pragma unroll
        for (int m = 0; m < MREP; ++m) {
            __syncthreads();
#pragma unroll
            for (int n = 0; n < 4; ++n)
#pragma unroll
                for (int r = 0; r < 4; ++r)
                    patch[(n * 16 + l15) * 20 + kc * 4 + r] = acc[m][n][r];
            __syncthreads();
#pragma unroll
            for (int t = 0; t < 4; ++t) {
                int qi = lane + t * 64;
                int col_ = qi >> 2, rq = qi & 3;
                float4 y = *(const float4*)&patch[col_ * 20 + rq * 4];
                int col = col0 + wc * 64 + col_;
                float bb = bias[col];
                y.x = silu_f(y.x + bb); y.y = silu_f(y.y + bb);
                y.z = silu_f(y.z + bb); y.w = silu_f(y.w + bb);
                int b = row0 >> 11;
                int seq = (row0 & 2047) + WRB + m * 16 + rq * 4;
                *(float4*)&OutF[(((size_t)(b * D1C + col)) << 11) + seq] = y;
            }
        }
    } else {
        float* patch = (float*)(smem + w * 4352);        // [16][68] f32, padded
#pragma unroll
        for (int m = 0; m < MREP; ++m) {
            __syncthreads();
#pragma unroll
            for (int n = 0; n < 4; ++n)
#pragma unroll
                for (int r = 0; r < 4; ++r)
                    patch[(kc * 4 + r) * 68 + n * 16 + l15] = acc[m][n][r];
            __syncthreads();
#pragma unroll
            for (int t = 0; t < 4; ++t) {
                int qi = lane + t * 64;
                int row_ = qi >> 4, q = qi & 15;
                float4 y = *(const float4*)&patch[row_ * 68 + q * 4];
                int row = row0 + WRB + m * 16 + row_;
                int col = col0 + wc * 64 + q * 4;
                float4 bb = *(const float4*)&bias[col];
                y.x += bb.x; y.y += bb.y; y.z += bb.z; y.w += bb.w;
                size_t idx = (size_t)row * Ncols + col;
                if constexpr (EPI == EP_SILU_F32) {
                    y.x = silu_f(y.x); y.y = silu_f(y.y);
                    y.z = silu_f(y.z); y.w = silu_f(y.w);
                    *(float4*)&OutF[idx] = y;
                } else if constexpr (EPI == EP_PLAIN) {
                    *(float4*)&OutF[idx] = y;
                } else {  // EP_GLU2
                    float4 e = *(const float4*)&E0[idx];
                    float z0 = e.x * y.x, z1 = e.y * y.y, z2 = e.z * y.z, z3 = e.w * y.w;
                    f16x4 h, l;
                    h[0] = (f16)z0; l[0] = (f16)(z0 - (float)h[0]);
                    h[1] = (f16)z1; l[1] = (f16)(z1 - (float)h[1]);
                    h[2] = (f16)z2; l[2] = (f16)(z2 - (float)h[2]);
                    h[3] = (f16)z3; l[3] = (f16)(z3 - (float)h[3]);
                    *(f16x4*)&OutH[idx] = h;
                    *(f16x4*)&OutL[idx] = l;
                }
            }
        }
    }
}

// ---------------------------------------------------------------------------
extern "C" void kernel_launch(void* const* d_in, const int* in_sizes, int n_in,
                              void* d_out, int out_size, void* d_ws, size_t ws_size,
                              hipStream_t stream) {
    const float* x   = (const float*)d_in[1];
    const float* u_w = (const float*)d_in[2];
    const float* u_b = (const float*)d_in[3];
    const float* v_w = (const float*)d_in[4];
    const float* v_b = (const float*)d_in[5];
    const float* o_w = (const float*)d_in[6];
    const float* o_b = (const float*)d_in[7];
    const float* rpw = (const float*)d_in[8];
    const float* rpb = (const float*)d_in[9];
    const float* rlw = (const float*)d_in[10];
    const float* rlb = (const float*)d_in[11];
    const float* row_w = (const float*)d_in[12];
    const float* rob = (const float*)d_in[13];
    const float* g1w = (const float*)d_in[14];
    const float* g1b = (const float*)d_in[15];
    const float* g2w = (const float*)d_in[16];
    const float* g2b = (const float*)d_in[17];
    const float* g3w = (const float*)d_in[18];
    const float* g3b = (const float*)d_in[19];

    char* wsb = (char*)d_ws;
    float* scale = (float*)wsb;                       // 64 KB slot
    char* R1 = wsb + (1 << 16);                       // af spectrum, later ph+pl
    char* R2 = R1 + 50331648;                         // vt, later tmp1
    char* R3 = R2 + 50331648;                         // a_r, then u, later zh+zl
    char* R4 = R3 + 50331648;                         // xn hi/lo, later x2 hi/lo
    char* R5 = R4 + 16777216;                         // 6 transposed f16 weights

    float2* af   = (float2*)R1;
    f16*    ph   = (f16*)R1;
    f16*    pl   = (f16*)(R1 + 25165824);
    float*  vt   = (float*)R2;
    float*  tmp1 = (float*)R2;
    float*  a_r  = (float*)R3;
    float*  u    = (float*)R3;
    f16*    zh   = (f16*)R3;
    f16*    zl   = (f16*)(R3 + 25165824);
    f16*    xnh  = (f16*)R4;
    f16*    xnl  = (f16*)(R4 + 8388608);
    f16*    x2h  = xnh;
    f16*    x2l  = xnl;

    auto wTh = [&](int i) { return (f16*)(R5 + (size_t)i * 1572864); };

    float* g_out   = (float*)d_out;
    float* out_out = g_out + (size_t)BATCH * NSEQ * EMBC;

    // prologue
    scale_kernel<<<2048, 256, 0, stream>>>(x, scale);
    convert_xn_kernel<<<4096, 256, 0, stream>>>(x, scale, xnh, xnl);
    wtrans_kernel<<<dim3(48, 16), 256, 0, stream>>>(u_w, wTh(0), 512, 1536);
    wtrans_kernel<<<dim3(48, 16), 256, 0, stream>>>(v_w, wTh(1), 512, 1536);
    wtrans_kernel<<<dim3(16, 48), 256, 0, stream>>>(o_w, wTh(2), 1536, 512);
    wtrans_kernel<<<dim3(48, 16), 256, 0, stream>>>(g1w, wTh(3), 512, 1536);
    wtrans_kernel<<<dim3(48, 16), 256, 0, stream>>>(g2w, wTh(4), 512, 1536);
    wtrans_kernel<<<dim3(16, 48), 256, 0, stream>>>(g3w, wTh(5), 1536, 512);
    rpe_kernel<<<64, 256, 0, stream>>>(rpw, rpb, rlw, rlb, row_w, rob, a_r);
    fft_a_kernel<<<1536, 256, 0, stream>>>(a_r, af);

    // u, v projections (M=8192, N=1536, K=512)
    mgemm<128, 512, EP_SILU_F32><<<768, 256, 0, stream>>>(
        xnh, xnl, wTh(0), u_b, nullptr, u, nullptr, nullptr, 1536);
    mgemm<128, 512, EP_SILU_VT><<<768, 256, 0, stream>>>(
        xnh, xnl, wTh(1), v_b, nullptr, vt, nullptr, nullptr, 1536);

    // Toeplitz via packed FFT conv, then p = u * t -> f16 split
    conv_kernel<<<3072, 256, 0, stream>>>(vt, af);
    convert_p_kernel<<<dim3(64, 48, 4), 256, 0, stream>>>(u, vt, ph, pl);

    // out = p @ o_w + o_b  (N=512, K=1536)
    mgemm<64, 1536, EP_PLAIN><<<512, 256, 0, stream>>>(
        ph, pl, wTh(2), o_b, nullptr, out_out, nullptr, nullptr, 512);

    // GLU
    convert_x2_kernel<<<4096, 256, 0, stream>>>(out_out, x, x2h, x2l);
    mgemm<128, 512, EP_SILU_F32><<<768, 256, 0, stream>>>(
        x2h, x2l, wTh(3), g1b, nullptr, tmp1, nullptr, nullptr, 1536);
    mgemm<128, 512, EP_GLU2><<<768, 256, 0, stream>>>(
        x2h, x2l, wTh(4), g2b, tmp1, nullptr, zh, zl, 1536);
    mgemm<64, 1536, EP_PLAIN><<<512, 256, 0, stream>>>(
        zh, zl, wTh(5), g3b, nullptr, g_out, nullptr, nullptr, 512);
}

// Round 6
// 584.167 us; speedup vs baseline: 1.1572x; 1.1572x over previous
//
#include <hip/hip_runtime.h>
#include <math.h>

#define NSEQ 2048
#define NFFT 4096
#define D1C  1536
#define EMBC 512
#define BATCH 4

typedef __fp16 f16;
typedef __fp16 f16x8 __attribute__((ext_vector_type(8)));
typedef __fp16 f16x4 __attribute__((ext_vector_type(4)));
typedef float  f32x4 __attribute__((ext_vector_type(4)));
typedef unsigned int u32;

__device__ __forceinline__ float silu_f(float y) { return y / (1.f + expf(-y)); }

// ---------------------------------------------------------------------------
// row-norm scale: scale[row] = 1/(||x_row|| * D1^-0.5 + 1e-8)
__global__ __launch_bounds__(256) void scale_kernel(const float* __restrict__ x,
                                                    float* __restrict__ scale) {
    int row  = blockIdx.x * 4 + (threadIdx.x >> 6);
    int lane = threadIdx.x & 63;
    const float* xr = x + (size_t)row * EMBC;
    float ss = 0.f;
#pragma unroll
    for (int k = 0; k < EMBC / 64; ++k) { float v = xr[lane + k * 64]; ss += v * v; }
#pragma unroll
    for (int off = 32; off >= 1; off >>= 1) ss += __shfl_xor(ss, off);
    if (lane == 0) scale[row] = 1.f / (sqrtf(ss) * 0.02551551815399144f + 1e-8f);
}

// xn = x * scale  -> f16 hi/lo
__global__ __launch_bounds__(256) void convert_xn_kernel(
    const float* __restrict__ x, const float* __restrict__ scale,
    f16* __restrict__ xh, f16* __restrict__ xl) {
    size_t i = ((size_t)blockIdx.x * 256 + threadIdx.x) * 4;
    float4 v = *reinterpret_cast<const float4*>(x + i);
    float s = scale[i >> 9];
    f16x4 h, l;
    const float* vv = (const float*)&v;
#pragma unroll
    for (int j = 0; j < 4; ++j) {
        float val = vv[j] * s;
        f16 hh = (f16)val;
        h[j] = hh; l[j] = (f16)(val - (float)hh);
    }
    *reinterpret_cast<f16x4*>(xh + i) = h;
    *reinterpret_cast<f16x4*>(xl + i) = l;
}

// x2 = a + b -> f16 hi/lo
__global__ __launch_bounds__(256) void convert_x2_kernel(
    const float* __restrict__ a, const float* __restrict__ b,
    f16* __restrict__ xh, f16* __restrict__ xl) {
    size_t i = ((size_t)blockIdx.x * 256 + threadIdx.x) * 4;
    float4 va = *reinterpret_cast<const float4*>(a + i);
    float4 vb = *reinterpret_cast<const float4*>(b + i);
    const float* pa = (const float*)&va;
    const float* pb = (const float*)&vb;
    f16x4 h, l;
#pragma unroll
    for (int j = 0; j < 4; ++j) {
        float val = pa[j] + pb[j];
        f16 hh = (f16)val;
        h[j] = hh; l[j] = (f16)(val - (float)hh);
    }
    *reinterpret_cast<f16x4*>(xh + i) = h;
    *reinterpret_cast<f16x4*>(xl + i) = l;
}

// W[K][N] fp32 -> WT[N][K] f16 hi only (LDS tile transpose)
__global__ __launch_bounds__(256) void wtrans_kernel(const float* __restrict__ W,
        f16* __restrict__ Th, int Kd, int Nd) {
    __shared__ float t[32][33];
    int tx = threadIdx.x & 31, ty = threadIdx.x >> 5;
    int n0 = blockIdx.x * 32, k0 = blockIdx.y * 32;
#pragma unroll
    for (int yy = ty; yy < 32; yy += 8)
        t[yy][tx] = W[(size_t)(k0 + yy) * Nd + n0 + tx];
    __syncthreads();
#pragma unroll
    for (int yy = ty; yy < 32; yy += 8) {
        float v = t[tx][yy];
        Th[(size_t)(n0 + yy) * Kd + k0 + tx] = (f16)v;
    }
}

// p = u * t (vt layout [b][col][n]) -> f16 hi/lo row-major [8192][1536]
__global__ __launch_bounds__(256) void convert_p_kernel(
    const float* __restrict__ u, const float* __restrict__ vt,
    f16* __restrict__ ph, f16* __restrict__ pl) {
    __shared__ float t[32][33];
    int b = blockIdx.z, n0 = blockIdx.x * 32, c0 = blockIdx.y * 32;
    int tx = threadIdx.x & 31, ty = threadIdx.x >> 5;
#pragma unroll
    for (int yy = ty; yy < 32; yy += 8)
        t[yy][tx] = vt[(((size_t)(b * D1C + c0 + yy)) << 11) + n0 + tx];
    __syncthreads();
#pragma unroll
    for (int yy = ty; yy < 32; yy += 8) {
        int row = b * NSEQ + n0 + yy;
        size_t idx = (size_t)row * D1C + c0 + tx;
        float val = u[idx] * t[tx][yy];
        f16 h = (f16)val;
        ph[idx] = h; pl[idx] = (f16)(val - (float)h);
    }
}

// ---------------------------------------------------------------------------
// RPE MLP (positions fully parallel): 4096 threads, one position each.
// Output hgT[k][pos] = relu(srms(h))[k]  (k = 0..31), fp32, coalesced stores.
__global__ __launch_bounds__(256) void rpe_mlp_kernel(
    const float* __restrict__ pw, const float* __restrict__ pb,
    const float* __restrict__ lw, const float* __restrict__ lb,
    float* __restrict__ hgT) {
    int s = blockIdx.x * 256 + threadIdx.x;
    float p = (s == 0 || s == 2048) ? 0.f : (s < 2048 ? (float)s : (float)(s - 4096));
    float h[32];
#pragma unroll
    for (int k = 0; k < 32; ++k) h[k] = fmaxf(p * pw[k] + pb[k], 0.f);
    for (int L = 0; L < 3; ++L) {
        float ss = 0.f;
#pragma unroll
        for (int k = 0; k < 32; ++k) ss += h[k] * h[k];
        float sc = 1.f / (sqrtf(ss) * 0.1767766952966369f + 1e-8f);
        float g[32];
#pragma unroll
        for (int k = 0; k < 32; ++k) g[k] = fmaxf(h[k] * sc, 0.f);
#pragma unroll
        for (int j = 0; j < 32; ++j) {
            float acc = lb[L * 32 + j];
#pragma unroll
            for (int k = 0; k < 32; ++k) acc += g[k] * lw[(L * 32 + k) * 32 + j];
            h[j] = acc;
        }
    }
    float ss = 0.f;
#pragma unroll
    for (int k = 0; k < 32; ++k) ss += h[k] * h[k];
    float sc = 1.f / (sqrtf(ss) * 0.1767766952966369f + 1e-8f);
#pragma unroll
    for (int k = 0; k < 32; ++k) hgT[(k << 12) + s] = fmaxf(h[k] * sc, 0.f);
}

// ---------------------------------------------------------------------------
// radix-16 register FFT, 4096 = 16^3, 256 threads, 16 pts/thread.
// Storage enumeration e = a*256 + b*16 + c; LDS pad phi(e) = e + 2*(e>>4).
// Spectrum stored/consumed at chi(q) = (q&15)*256 + (q>>4).
#define LIDX(e) ((e) + ((((e) >> 4)) << 1))

// In-place 16-point DFT: x[k] = sum_n x[n] * W16^{+-nk}  (INV: +, fwd: -)
// HALF: inputs n=8..15 are zero (not read).
template <bool INV, bool HALF>
__device__ __forceinline__ void dft16(float* xr, float* xi) {
    constexpr float C1 = 0.92387953251f, S1 = 0.38268343236f, R2 = 0.70710678119f;
    constexpr float sg = INV ? 1.f : -1.f;
    float tr[16], ti[16];
#pragma unroll
    for (int n0 = 0; n0 < 4; ++n0) {
        float ar = xr[n0], ai = xi[n0];
        float br = xr[n0 + 4], bi = xi[n0 + 4];
        float j0r, j0i, j1r, j1i, j2r, j2i, j3r, j3i;
        if constexpr (HALF) {
            j0r = ar + br; j0i = ai + bi;
            j2r = ar - br; j2i = ai - bi;
            if constexpr (!INV) { j1r = ar + bi; j1i = ai - br; j3r = ar - bi; j3i = ai + br; }
            else                { j1r = ar - bi; j1i = ai + br; j3r = ar + bi; j3i = ai - br; }
        } else {
            float cr = xr[n0 + 8],  ci = xi[n0 + 8];
            float dr = xr[n0 + 12], di = xi[n0 + 12];
            float t0r = ar + cr, t0i = ai + ci;
            float t1r = ar - cr, t1i = ai - ci;
            float t2r = br + dr, t2i = bi + di;
            float t3r = br - dr, t3i = bi - di;
            j0r = t0r + t2r; j0i = t0i + t2i;
            j2r = t0r - t2r; j2i = t0i - t2i;
            if constexpr (!INV) { j1r = t1r + t3i; j1i = t1i - t3r;
                                  j3r = t1r - t3i; j3i = t1i + t3r; }
            else                { j1r = t1r - t3i; j1i = t1i + t3r;
                                  j3r = t1r + t3i; j3i = t1i - t3r; }
        }
        tr[n0] = j0r;      ti[n0] = j0i;
        tr[n0 + 4] = j1r;  ti[n0 + 4] = j1i;
        tr[n0 + 8] = j2r;  ti[n0 + 8] = j2i;
        tr[n0 + 12] = j3r; ti[n0 + 12] = j3i;
    }
#define CMK(idx, wr_, wi_) { float _r = tr[idx], _i = ti[idx]; \
        tr[idx] = _r * (wr_) - _i * (wi_); ti[idx] = _r * (wi_) + _i * (wr_); }
    CMK(5,  C1, sg * S1)  CMK(6,  R2, sg * R2)  CMK(7,  S1, sg * C1)
    CMK(9,  R2, sg * R2)
    { float _r = tr[10];
      if constexpr (!INV) { tr[10] = ti[10];  ti[10] = -_r; }
      else                { tr[10] = -ti[10]; ti[10] = _r;  } }
    CMK(11, -R2, sg * R2)
    CMK(13, S1, sg * C1)  CMK(14, -R2, sg * R2)  CMK(15, -C1, -sg * S1)
#undef CMK
#pragma unroll
    for (int j = 0; j < 4; ++j) {
        float ar = tr[4 * j],     ai = ti[4 * j];
        float br = tr[4 * j + 1], bi = ti[4 * j + 1];
        float cr = tr[4 * j + 2], ci = ti[4 * j + 2];
        float dr = tr[4 * j + 3], di = ti[4 * j + 3];
        float t0r = ar + cr, t0i = ai + ci;
        float t1r = ar - cr, t1i = ai - ci;
        float t2r = br + dr, t2i = bi + di;
        float t3r = br - dr, t3i = bi - di;
        xr[j]      = t0r + t2r; xi[j]      = t0i + t2i;
        xr[8 + j]  = t0r - t2r; xi[8 + j]  = t0i - t2i;
        if constexpr (!INV) {
            xr[4 + j]  = t1r + t3i; xi[4 + j]  = t1i - t3r;
            xr[12 + j] = t1r - t3i; xi[12 + j] = t1i + t3r;
        } else {
            xr[4 + j]  = t1r - t3i; xi[4 + j]  = t1i + t3r;
            xr[12 + j] = t1r + t3i; xi[12 + j] = t1i - t3r;
        }
    }
}

#define CMUL_ADV(wr, wi, sr, si) { float _n = (wr)*(sr) - (wi)*(si); \
        (wi) = (wr)*(si) + (wi)*(sr); (wr) = _n; }

// fused RPE projection (per-col dot over hgT) + forward FFT -> af (chi order)
__global__ __launch_bounds__(256, 3) void fft_a_kernel(
    const float* __restrict__ hgT, const float* __restrict__ ow,
    const float* __restrict__ ob, float2* __restrict__ af) {
    __shared__ float2 buf[4608];
    int tid = threadIdx.x;
    int col = blockIdx.x;
    float2* orow = af + ((size_t)col << 12);
    float xr[16], xi[16];
    float bsr, bsi, wr, wi;
    // stage 1 input computed on the fly: a_r[e] = ob[col] + sum_k hgT[k][e]*ow[k][col]
    float obc = ob[col];
#pragma unroll
    for (int a = 0; a < 16; ++a) { xr[a] = obc; xi[a] = 0.f; }
    for (int k = 0; k < 32; ++k) {
        float wk = ow[k * D1C + col];
        const float* hrow = hgT + (k << 12) + tid;
#pragma unroll
        for (int a = 0; a < 16; ++a) xr[a] = fmaf(hrow[a * 256], wk, xr[a]);
    }
    dft16<false, false>(xr, xi);
    __sincosf(-(float)M_PI / 2048.f * (float)tid, &bsi, &bsr);
    wr = bsr; wi = bsi;
    buf[LIDX(tid)] = make_float2(xr[0], xi[0]);
#pragma unroll
    for (int k0 = 1; k0 < 16; ++k0) {
        buf[LIDX(k0 * 256 + tid)] =
            make_float2(xr[k0] * wr - xi[k0] * wi, xr[k0] * wi + xi[k0] * wr);
        CMUL_ADV(wr, wi, bsr, bsi);
    }
    __syncthreads();
    // stage 2: b-axis (stride 16)
    int k0 = tid >> 4, cc = tid & 15;
    int base2 = k0 * 256 + cc;
#pragma unroll
    for (int b = 0; b < 16; ++b) {
        float2 v = buf[LIDX(base2 + b * 16)]; xr[b] = v.x; xi[b] = v.y;
    }
    dft16<false, false>(xr, xi);
    __sincosf(-(float)M_PI / 128.f * (float)cc, &bsi, &bsr);
    wr = bsr; wi = bsi;
    buf[LIDX(base2)] = make_float2(xr[0], xi[0]);
#pragma unroll
    for (int k1 = 1; k1 < 16; ++k1) {
        buf[LIDX(base2 + k1 * 16)] =
            make_float2(xr[k1] * wr - xi[k1] * wi, xr[k1] * wi + xi[k1] * wr);
        CMUL_ADV(wr, wi, bsr, bsi);
    }
    __syncthreads();
    // stage 3: c-axis (contiguous b128 loads), store chi-transposed
    const float4* pld = (const float4*)&buf[18 * tid];
#pragma unroll
    for (int h = 0; h < 8; ++h) {
        float4 q = pld[h];
        xr[2 * h] = q.x; xi[2 * h] = q.y; xr[2 * h + 1] = q.z; xi[2 * h + 1] = q.w;
    }
    dft16<false, false>(xr, xi);
#pragma unroll
    for (int k2 = 0; k2 < 16; ++k2)
        orow[k2 * 256 + tid] = make_float2(xr[k2], xi[k2]);
}

// packed circular convolution: z = v[b0] + i*v[b1]; fwd FFT -> *af -> inv FFT
__global__ __launch_bounds__(256, 3) void conv_kernel(float* __restrict__ vt,
                                                      const float2* __restrict__ af) {
    __shared__ float2 buf[4608];
    int tid = threadIdx.x;
    int pr  = blockIdx.x / D1C;
    int col = blockIdx.x % D1C;
    float* v0 = vt + ((size_t)((2 * pr)     * D1C + col) << 11);
    float* v1 = vt + ((size_t)((2 * pr + 1) * D1C + col) << 11);
    const float2* arow = af + ((size_t)col << 12);
    float xr[16], xi[16];
    float bsr, bsi, wr, wi;

    // ---- fwd stage 1 (a-axis), upper half zero
#pragma unroll
    for (int a = 0; a < 8; ++a) { xr[a] = v0[a * 256 + tid]; xi[a] = v1[a * 256 + tid]; }
    dft16<false, true>(xr, xi);
    __sincosf(-(float)M_PI / 2048.f * (float)tid, &bsi, &bsr);
    wr = bsr; wi = bsi;
    buf[LIDX(tid)] = make_float2(xr[0], xi[0]);
#pragma unroll
    for (int k0 = 1; k0 < 16; ++k0) {
        buf[LIDX(k0 * 256 + tid)] =
            make_float2(xr[k0] * wr - xi[k0] * wi, xr[k0] * wi + xi[k0] * wr);
        CMUL_ADV(wr, wi, bsr, bsi);
    }
    __syncthreads();
    // ---- fwd stage 2 (b-axis)
    int k0 = tid >> 4, cc = tid & 15;
    int base2 = k0 * 256 + cc;
#pragma unroll
    for (int b = 0; b < 16; ++b) {
        float2 v = buf[LIDX(base2 + b * 16)]; xr[b] = v.x; xi[b] = v.y;
    }
    dft16<false, false>(xr, xi);
    __sincosf(-(float)M_PI / 128.f * (float)cc, &bsi, &bsr);
    wr = bsr; wi = bsi;
    buf[LIDX(base2)] = make_float2(xr[0], xi[0]);
#pragma unroll
    for (int k1 = 1; k1 < 16; ++k1) {
        buf[LIDX(base2 + k1 * 16)] =
            make_float2(xr[k1] * wr - xi[k1] * wi, xr[k1] * wi + xi[k1] * wr);
        CMUL_ADV(wr, wi, bsr, bsi);
    }
    __syncthreads();
    // ---- fwd stage 3 (registers) + pointwise + inv stage A (fused)
    const float4* pld = (const float4*)&buf[18 * tid];
#pragma unroll
    for (int h = 0; h < 8; ++h) {
        float4 q = pld[h];
        xr[2 * h] = q.x; xi[2 * h] = q.y; xr[2 * h + 1] = q.z; xi[2 * h + 1] = q.w;
    }
    dft16<false, false>(xr, xi);
    const float inv = 1.0f / 4096.0f;
#pragma unroll
    for (int k2 = 0; k2 < 16; ++k2) {
        float2 w = arow[k2 * 256 + tid];
        float rr = (xr[k2] * w.x - xi[k2] * w.y) * inv;
        float ii = (xr[k2] * w.y + xi[k2] * w.x) * inv;
        xr[k2] = rr; xi[k2] = ii;
    }
    dft16<true, false>(xr, xi);                   // IDFT over k2 -> c
    __sincosf((float)M_PI / 128.f * (float)cc, &bsi, &bsr);  // W^{+16*k1} base
    wr = bsr; wi = bsi;
#pragma unroll
    for (int c = 1; c < 16; ++c) {
        float rr = xr[c] * wr - xi[c] * wi;
        xi[c] = xr[c] * wi + xi[c] * wr; xr[c] = rr;
        CMUL_ADV(wr, wi, bsr, bsi);
    }
    float4* pst = (float4*)&buf[18 * tid];
#pragma unroll
    for (int h = 0; h < 8; ++h)
        pst[h] = make_float4(xr[2 * h], xi[2 * h], xr[2 * h + 1], xi[2 * h + 1]);
    __syncthreads();
    // ---- inv stage B (k1-axis -> b), * W^{+k0(16b+c)}
#pragma unroll
    for (int k1 = 0; k1 < 16; ++k1) {
        float2 v = buf[LIDX(base2 + k1 * 16)]; xr[k1] = v.x; xi[k1] = v.y;
    }
    dft16<true, false>(xr, xi);
    float swr, swi;
    __sincosf((float)M_PI / 2048.f * (float)(k0 * cc), &bsi, &bsr);  // W^{+k0*c}
    __sincosf((float)M_PI / 128.f * (float)k0, &swi, &swr);          // W^{+16*k0}
    wr = bsr; wi = bsi;
#pragma unroll
    for (int b = 0; b < 16; ++b) {
        buf[LIDX(base2 + b * 16)] =
            make_float2(xr[b] * wr - xi[b] * wi, xr[b] * wi + xi[b] * wr);
        CMUL_ADV(wr, wi, swr, swi);
    }
    __syncthreads();
    // ---- inv stage C (k0-axis -> a), store first half
#pragma unroll
    for (int k = 0; k < 16; ++k) {
        float2 v = buf[LIDX(k * 256 + tid)]; xr[k] = v.x; xi[k] = v.y;
    }
    dft16<true, false>(xr, xi);
#pragma unroll
    for (int a = 0; a < 8; ++a) {
        v0[a * 256 + tid] = xr[a];
        v1[a * 256 + tid] = xi[a];
    }
}

// ---------------------------------------------------------------------------
// MFMA 2-pass split-f16 GEMM: C = (Ah+Al)*Bh, fp32 accum (B rounded to f16).
enum { EP_SILU_F32, EP_SILU_VT, EP_PLAIN, EP_GLU2 };

template <int BM, int K, int EPI>
__global__ __launch_bounds__(256, (BM == 128 ? 3 : 4)) void mgemm(
    const f16* __restrict__ Ah, const f16* __restrict__ Al,
    const f16* __restrict__ Bh,
    const float* __restrict__ bias, const float* __restrict__ E0,
    float* __restrict__ OutF, f16* __restrict__ OutH, f16* __restrict__ OutL,
    int Ncols) {
    constexpr int SB   = BM * 128 + 8192;
    constexpr int MREP = BM / 32;
    constexpr int LOGB = (BM == 128 ? 7 : 6);
    constexpr int CA   = BM / 64;
    __shared__ __align__(16) char smem[2 * SB];

    const int tid  = threadIdx.x;
    const int w    = tid >> 6, lane = tid & 63;
    const int wr   = w >> 1, wc = w & 1;
    const int l15  = lane & 15, kc = lane >> 4;

    const int NBY = Ncols >> 7;
    const int nwg = gridDim.x;
    int flat = blockIdx.x;
    int q8 = nwg >> 3, r8 = nwg & 7;
    int xcd = flat & 7, pos = flat >> 3;
    int wg = (xcd < r8 ? xcd * (q8 + 1) : r8 * (q8 + 1) + (xcd - r8) * q8) + pos;
    const int row0 = (wg / NBY) * BM;
    const int col0 = (wg % NBY) * 128;

    f32x4 acc[MREP][4] = {};

    auto stage = [&](int buf, int kt) {
        const int k0 = kt * 32;
        const int bb = buf * SB;
#pragma unroll
        for (int l = 0; l < CA; ++l) {
            int ci = tid + l * 256;
            int r = ci & (BM - 1), kk = ci >> LOGB;
            const f16* ga = Ah + (size_t)(row0 + r) * K + k0 + kk * 8;
            const f16* gb = Al + (size_t)(row0 + r) * K + k0 + kk * 8;
            __builtin_amdgcn_global_load_lds((const __attribute__((address_space(1))) u32*)ga,
                (__attribute__((address_space(3))) u32*)(smem + bb + ci * 16), 16, 0, 0);
            __builtin_amdgcn_global_load_lds((const __attribute__((address_space(1))) u32*)gb,
                (__attribute__((address_space(3))) u32*)(smem + bb + BM * 64 + ci * 16), 16, 0, 0);
        }
#pragma unroll
        for (int l = 0; l < 2; ++l) {
            int ci = tid + l * 256;
            int c = ci & 127, kk = ci >> 7;
            const f16* gc = Bh + (size_t)(col0 + c) * K + k0 + kk * 8;
            __builtin_amdgcn_global_load_lds((const __attribute__((address_space(1))) u32*)gc,
                (__attribute__((address_space(3))) u32*)(smem + bb + BM * 128 + ci * 16), 16, 0, 0);
        }
    };

    auto compute = [&](int buf) {
        const char* base = smem + buf * SB;
        f16x8 a_h[MREP], a_l[MREP], b_h[4];
#pragma unroll
        for (int m = 0; m < MREP; ++m) {
            int r = wr * (BM / 2) + m * 16 + l15;
            a_h[m] = *(const f16x8*)(base + (kc * BM + r) * 16);
            a_l[m] = *(const f16x8*)(base + BM * 64 + (kc * BM + r) * 16);
        }
#pragma unroll
        for (int n = 0; n < 4; ++n) {
            int c = wc * 64 + n * 16 + l15;
            b_h[n] = *(const f16x8*)(base + BM * 128 + (kc * 128 + c) * 16);
        }
#pragma unroll
        for (int m = 0; m < MREP; ++m)
#pragma unroll
            for (int n = 0; n < 4; ++n) {
                acc[m][n] = __builtin_amdgcn_mfma_f32_16x16x32_f16(a_h[m], b_h[n], acc[m][n], 0, 0, 0);
                acc[m][n] = __builtin_amdgcn_mfma_f32_16x16x32_f16(a_l[m], b_h[n], acc[m][n], 0, 0, 0);
            }
    };

    constexpr int NT = K / 32;
    stage(0, 0);
    __syncthreads();
    int cur = 0;
    for (int t = 0; t < NT; ++t) {
        if (t + 1 < NT) stage(cur ^ 1, t + 1);
        compute(cur);
        __syncthreads();
        cur ^= 1;
    }

    const int WRB = wr * (BM / 2);
    if constexpr (EPI == EP_SILU_VT) {
        float* patch = (float*)(smem + w * 5376);        // [64][20] f32, padded
#pragma unroll
        for (int m = 0; m < MREP; ++m) {
            __syncthreads();
#pragma unroll
            for (int n = 0; n < 4; ++n)
#pragma unroll
                for (int r = 0; r < 4; ++r)
                    patch[(n * 16 + l15) * 20 + kc * 4 + r] = acc[m][n][r];
            __syncthreads();
#pragma unroll
            for (int t = 0; t < 4; ++t) {
                int qi = lane + t * 64;
                int col_ = qi >> 2, rq = qi & 3;
                float4 y = *(const float4*)&patch[col_ * 20 + rq * 4];
                int col = col0 + wc * 64 + col_;
                float bb = bias[col];
                y.x = silu_f(y.x + bb); y.y = silu_f(y.y + bb);
                y.z = silu_f(y.z + bb); y.w = silu_f(y.w + bb);
                int b = row0 >> 11;
                int seq = (row0 & 2047) + WRB + m * 16 + rq * 4;
                *(float4*)&OutF[(((size_t)(b * D1C + col)) << 11) + seq] = y;
            }
        }
    } else {
        float* patch = (float*)(smem + w * 4352);        // [16][68] f32, padded
#pragma unroll
        for (int m = 0; m < MREP; ++m) {
            __syncthreads();
#pragma unroll
            for (int n = 0; n < 4; ++n)
#pragma unroll
                for (int r = 0; r < 4; ++r)
                    patch[(kc * 4 + r) * 68 + n * 16 + l15] = acc[m][n][r];
            __syncthreads();
#pragma unroll
            for (int t = 0; t < 4; ++t) {
                int qi = lane + t * 64;
                int row_ = qi >> 4, q = qi & 15;
                float4 y = *(const float4*)&patch[row_ * 68 + q * 4];
                int row = row0 + WRB + m * 16 + row_;
                int col = col0 + wc * 64 + q * 4;
                float4 bb = *(const float4*)&bias[col];
                y.x += bb.x; y.y += bb.y; y.z += bb.z; y.w += bb.w;
                size_t idx = (size_t)row * Ncols + col;
                if constexpr (EPI == EP_SILU_F32) {
                    y.x = silu_f(y.x); y.y = silu_f(y.y);
                    y.z = silu_f(y.z); y.w = silu_f(y.w);
                    *(float4*)&OutF[idx] = y;
                } else if constexpr (EPI == EP_PLAIN) {
                    *(float4*)&OutF[idx] = y;
                } else {  // EP_GLU2
                    float4 e = *(const float4*)&E0[idx];
                    float z0 = e.x * y.x, z1 = e.y * y.y, z2 = e.z * y.z, z3 = e.w * y.w;
                    f16x4 h, l;
                    h[0] = (f16)z0; l[0] = (f16)(z0 - (float)h[0]);
                    h[1] = (f16)z1; l[1] = (f16)(z1 - (float)h[1]);
                    h[2] = (f16)z2; l[2] = (f16)(z2 - (float)h[2]);
                    h[3] = (f16)z3; l[3] = (f16)(z3 - (float)h[3]);
                    *(f16x4*)&OutH[idx] = h;
                    *(f16x4*)&OutL[idx] = l;
                }
            }
        }
    }
}

// ---------------------------------------------------------------------------
extern "C" void kernel_launch(void* const* d_in, const int* in_sizes, int n_in,
                              void* d_out, int out_size, void* d_ws, size_t ws_size,
                              hipStream_t stream) {
    const float* x   = (const float*)d_in[1];
    const float* u_w = (const float*)d_in[2];
    const float* u_b = (const float*)d_in[3];
    const float* v_w = (const float*)d_in[4];
    const float* v_b = (const float*)d_in[5];
    const float* o_w = (const float*)d_in[6];
    const float* o_b = (const float*)d_in[7];
    const float* rpw = (const float*)d_in[8];
    const float* rpb = (const float*)d_in[9];
    const float* rlw = (const float*)d_in[10];
    const float* rlb = (const float*)d_in[11];
    const float* row_w = (const float*)d_in[12];
    const float* rob = (const float*)d_in[13];
    const float* g1w = (const float*)d_in[14];
    const float* g1b = (const float*)d_in[15];
    const float* g2w = (const float*)d_in[16];
    const float* g2b = (const float*)d_in[17];
    const float* g3w = (const float*)d_in[18];
    const float* g3b = (const float*)d_in[19];

    char* wsb = (char*)d_ws;
    float* scale = (float*)wsb;                       // 64 KB slot
    char* R1 = wsb + (1 << 16);                       // af spectrum, later ph+pl
    char* R2 = R1 + 50331648;                         // vt, later tmp1
    char* R3 = R2 + 50331648;                         // hgT, then u, later zh+zl
    char* R4 = R3 + 50331648;                         // xn hi/lo, later x2 hi/lo
    char* R5 = R4 + 16777216;                         // 6 transposed f16 weights

    float2* af   = (float2*)R1;
    f16*    ph   = (f16*)R1;
    f16*    pl   = (f16*)(R1 + 25165824);
    float*  vt   = (float*)R2;
    float*  tmp1 = (float*)R2;
    float*  hgT  = (float*)R3;   // dead before u is written
    float*  u    = (float*)R3;
    f16*    zh   = (f16*)R3;
    f16*    zl   = (f16*)(R3 + 25165824);
    f16*    xnh  = (f16*)R4;
    f16*    xnl  = (f16*)(R4 + 8388608);
    f16*    x2h  = xnh;
    f16*    x2l  = xnl;

    auto wTh = [&](int i) { return (f16*)(R5 + (size_t)i * 1572864); };

    float* g_out   = (float*)d_out;
    float* out_out = g_out + (size_t)BATCH * NSEQ * EMBC;

    // prologue
    scale_kernel<<<2048, 256, 0, stream>>>(x, scale);
    convert_xn_kernel<<<4096, 256, 0, stream>>>(x, scale, xnh, xnl);
    wtrans_kernel<<<dim3(48, 16), 256, 0, stream>>>(u_w, wTh(0), 512, 1536);
    wtrans_kernel<<<dim3(48, 16), 256, 0, stream>>>(v_w, wTh(1), 512, 1536);
    wtrans_kernel<<<dim3(16, 48), 256, 0, stream>>>(o_w, wTh(2), 1536, 512);
    wtrans_kernel<<<dim3(48, 16), 256, 0, stream>>>(g1w, wTh(3), 512, 1536);
    wtrans_kernel<<<dim3(48, 16), 256, 0, stream>>>(g2w, wTh(4), 512, 1536);
    wtrans_kernel<<<dim3(16, 48), 256, 0, stream>>>(g3w, wTh(5), 1536, 512);
    rpe_mlp_kernel<<<16, 256, 0, stream>>>(rpw, rpb, rlw, rlb, hgT);
    fft_a_kernel<<<1536, 256, 0, stream>>>(hgT, row_w, rob, af);

    // u, v projections (M=8192, N=1536, K=512)
    mgemm<128, 512, EP_SILU_F32><<<768, 256, 0, stream>>>(
        xnh, xnl, wTh(0), u_b, nullptr, u, nullptr, nullptr, 1536);
    mgemm<128, 512, EP_SILU_VT><<<768, 256, 0, stream>>>(
        xnh, xnl, wTh(1), v_b, nullptr, vt, nullptr, nullptr, 1536);

    // Toeplitz via packed FFT conv, then p = u * t -> f16 split
    conv_kernel<<<3072, 256, 0, stream>>>(vt, af);
    convert_p_kernel<<<dim3(64, 48, 4), 256, 0, stream>>>(u, vt, ph, pl);

    // out = p @ o_w + o_b  (N=512, K=1536)
    mgemm<64, 1536, EP_PLAIN><<<512, 256, 0, stream>>>(
        ph, pl, wTh(2), o_b, nullptr, out_out, nullptr, nullptr, 512);

    // GLU
    convert_x2_kernel<<<4096, 256, 0, stream>>>(out_out, x, x2h, x2l);
    mgemm<128, 512, EP_SILU_F32><<<768, 256, 0, stream>>>(
        x2h, x2l, wTh(3), g1b, nullptr, tmp1, nullptr, nullptr, 1536);
    mgemm<128, 512, EP_GLU2><<<768, 256, 0, stream>>>(
        x2h, x2l, wTh(4), g2b, tmp1, nullptr, zh, zl, 1536);
    mgemm<64, 1536, EP_PLAIN><<<512, 256, 0, stream>>>(
        zh, zl, wTh(5), g3b, nullptr, g_out, nullptr, nullptr, 512);
}

// Round 7
// 575.112 us; speedup vs baseline: 1.1754x; 1.0157x over previous
//
#include <hip/hip_runtime.h>
#include <math.h>

#define NSEQ 2048
#define NFFT 4096
#define D1C  1536
#define EMBC 512
#define BATCH 4

typedef __fp16 f16;
typedef __fp16 f16x8 __attribute__((ext_vector_type(8)));
typedef __fp16 f16x4 __attribute__((ext_vector_type(4)));
typedef float  f32x4 __attribute__((ext_vector_type(4)));
typedef unsigned int u32;

__device__ __forceinline__ float silu_f(float y) { return y / (1.f + expf(-y)); }

// ---------------------------------------------------------------------------
// row-norm scale: scale[row] = 1/(||x_row|| * D1^-0.5 + 1e-8)
__global__ __launch_bounds__(256) void scale_kernel(const float* __restrict__ x,
                                                    float* __restrict__ scale) {
    int row  = blockIdx.x * 4 + (threadIdx.x >> 6);
    int lane = threadIdx.x & 63;
    const float* xr = x + (size_t)row * EMBC;
    float ss = 0.f;
#pragma unroll
    for (int k = 0; k < EMBC / 64; ++k) { float v = xr[lane + k * 64]; ss += v * v; }
#pragma unroll
    for (int off = 32; off >= 1; off >>= 1) ss += __shfl_xor(ss, off);
    if (lane == 0) scale[row] = 1.f / (sqrtf(ss) * 0.02551551815399144f + 1e-8f);
}

// xn = x * scale  -> f16 hi/lo
__global__ __launch_bounds__(256) void convert_xn_kernel(
    const float* __restrict__ x, const float* __restrict__ scale,
    f16* __restrict__ xh, f16* __restrict__ xl) {
    size_t i = ((size_t)blockIdx.x * 256 + threadIdx.x) * 4;
    float4 v = *reinterpret_cast<const float4*>(x + i);
    float s = scale[i >> 9];
    f16x4 h, l;
    const float* vv = (const float*)&v;
#pragma unroll
    for (int j = 0; j < 4; ++j) {
        float val = vv[j] * s;
        f16 hh = (f16)val;
        h[j] = hh; l[j] = (f16)(val - (float)hh);
    }
    *reinterpret_cast<f16x4*>(xh + i) = h;
    *reinterpret_cast<f16x4*>(xl + i) = l;
}

// x2 = a + b -> f16 hi/lo
__global__ __launch_bounds__(256) void convert_x2_kernel(
    const float* __restrict__ a, const float* __restrict__ b,
    f16* __restrict__ xh, f16* __restrict__ xl) {
    size_t i = ((size_t)blockIdx.x * 256 + threadIdx.x) * 4;
    float4 va = *reinterpret_cast<const float4*>(a + i);
    float4 vb = *reinterpret_cast<const float4*>(b + i);
    const float* pa = (const float*)&va;
    const float* pb = (const float*)&vb;
    f16x4 h, l;
#pragma unroll
    for (int j = 0; j < 4; ++j) {
        float val = pa[j] + pb[j];
        f16 hh = (f16)val;
        h[j] = hh; l[j] = (f16)(val - (float)hh);
    }
    *reinterpret_cast<f16x4*>(xh + i) = h;
    *reinterpret_cast<f16x4*>(xl + i) = l;
}

// W[K][N] fp32 -> WT[N][K] f16 hi only (LDS tile transpose)
__global__ __launch_bounds__(256) void wtrans_kernel(const float* __restrict__ W,
        f16* __restrict__ Th, int Kd, int Nd) {
    __shared__ float t[32][33];
    int tx = threadIdx.x & 31, ty = threadIdx.x >> 5;
    int n0 = blockIdx.x * 32, k0 = blockIdx.y * 32;
#pragma unroll
    for (int yy = ty; yy < 32; yy += 8)
        t[yy][tx] = W[(size_t)(k0 + yy) * Nd + n0 + tx];
    __syncthreads();
#pragma unroll
    for (int yy = ty; yy < 32; yy += 8) {
        float v = t[tx][yy];
        Th[(size_t)(n0 + yy) * Kd + k0 + tx] = (f16)v;
    }
}

// p = u * t (vt layout [b][col][n]) -> f16 hi/lo row-major [8192][1536]
__global__ __launch_bounds__(256) void convert_p_kernel(
    const float* __restrict__ u, const float* __restrict__ vt,
    f16* __restrict__ ph, f16* __restrict__ pl) {
    __shared__ float t[32][33];
    int b = blockIdx.z, n0 = blockIdx.x * 32, c0 = blockIdx.y * 32;
    int tx = threadIdx.x & 31, ty = threadIdx.x >> 5;
#pragma unroll
    for (int yy = ty; yy < 32; yy += 8)
        t[yy][tx] = vt[(((size_t)(b * D1C + c0 + yy)) << 11) + n0 + tx];
    __syncthreads();
#pragma unroll
    for (int yy = ty; yy < 32; yy += 8) {
        int row = b * NSEQ + n0 + yy;
        size_t idx = (size_t)row * D1C + c0 + tx;
        float val = u[idx] * t[tx][yy];
        f16 h = (f16)val;
        ph[idx] = h; pl[idx] = (f16)(val - (float)h);
    }
}

// ---------------------------------------------------------------------------
// RPE MLP (positions fully parallel): 4096 threads, one position each.
__global__ __launch_bounds__(256) void rpe_mlp_kernel(
    const float* __restrict__ pw, const float* __restrict__ pb,
    const float* __restrict__ lw, const float* __restrict__ lb,
    float* __restrict__ hgT) {
    int s = blockIdx.x * 256 + threadIdx.x;
    float p = (s == 0 || s == 2048) ? 0.f : (s < 2048 ? (float)s : (float)(s - 4096));
    float h[32];
#pragma unroll
    for (int k = 0; k < 32; ++k) h[k] = fmaxf(p * pw[k] + pb[k], 0.f);
    for (int L = 0; L < 3; ++L) {
        float ss = 0.f;
#pragma unroll
        for (int k = 0; k < 32; ++k) ss += h[k] * h[k];
        float sc = 1.f / (sqrtf(ss) * 0.1767766952966369f + 1e-8f);
        float g[32];
#pragma unroll
        for (int k = 0; k < 32; ++k) g[k] = fmaxf(h[k] * sc, 0.f);
#pragma unroll
        for (int j = 0; j < 32; ++j) {
            float acc = lb[L * 32 + j];
#pragma unroll
            for (int k = 0; k < 32; ++k) acc += g[k] * lw[(L * 32 + k) * 32 + j];
            h[j] = acc;
        }
    }
    float ss = 0.f;
#pragma unroll
    for (int k = 0; k < 32; ++k) ss += h[k] * h[k];
    float sc = 1.f / (sqrtf(ss) * 0.1767766952966369f + 1e-8f);
#pragma unroll
    for (int k = 0; k < 32; ++k) hgT[(k << 12) + s] = fmaxf(h[k] * sc, 0.f);
}

// ---------------------------------------------------------------------------
// radix-16 register FFT, 4096 = 16^3, 256 threads, 16 pts/thread.
#define LIDX(e) ((e) + ((((e) >> 4)) << 1))

template <bool INV, bool HALF>
__device__ __forceinline__ void dft16(float* xr, float* xi) {
    constexpr float C1 = 0.92387953251f, S1 = 0.38268343236f, R2 = 0.70710678119f;
    constexpr float sg = INV ? 1.f : -1.f;
    float tr[16], ti[16];
#pragma unroll
    for (int n0 = 0; n0 < 4; ++n0) {
        float ar = xr[n0], ai = xi[n0];
        float br = xr[n0 + 4], bi = xi[n0 + 4];
        float j0r, j0i, j1r, j1i, j2r, j2i, j3r, j3i;
        if constexpr (HALF) {
            j0r = ar + br; j0i = ai + bi;
            j2r = ar - br; j2i = ai - bi;
            if constexpr (!INV) { j1r = ar + bi; j1i = ai - br; j3r = ar - bi; j3i = ai + br; }
            else                { j1r = ar - bi; j1i = ai + br; j3r = ar + bi; j3i = ai - br; }
        } else {
            float cr = xr[n0 + 8],  ci = xi[n0 + 8];
            float dr = xr[n0 + 12], di = xi[n0 + 12];
            float t0r = ar + cr, t0i = ai + ci;
            float t1r = ar - cr, t1i = ai - ci;
            float t2r = br + dr, t2i = bi + di;
            float t3r = br - dr, t3i = bi - di;
            j0r = t0r + t2r; j0i = t0i + t2i;
            j2r = t0r - t2r; j2i = t0i - t2i;
            if constexpr (!INV) { j1r = t1r + t3i; j1i = t1i - t3r;
                                  j3r = t1r - t3i; j3i = t1i + t3r; }
            else                { j1r = t1r - t3i; j1i = t1i + t3r;
                                  j3r = t1r + t3i; j3i = t1i - t3r; }
        }
        tr[n0] = j0r;      ti[n0] = j0i;
        tr[n0 + 4] = j1r;  ti[n0 + 4] = j1i;
        tr[n0 + 8] = j2r;  ti[n0 + 8] = j2i;
        tr[n0 + 12] = j3r; ti[n0 + 12] = j3i;
    }
#define CMK(idx, wr_, wi_) { float _r = tr[idx], _i = ti[idx]; \
        tr[idx] = _r * (wr_) - _i * (wi_); ti[idx] = _r * (wi_) + _i * (wr_); }
    CMK(5,  C1, sg * S1)  CMK(6,  R2, sg * R2)  CMK(7,  S1, sg * C1)
    CMK(9,  R2, sg * R2)
    { float _r = tr[10];
      if constexpr (!INV) { tr[10] = ti[10];  ti[10] = -_r; }
      else                { tr[10] = -ti[10]; ti[10] = _r;  } }
    CMK(11, -R2, sg * R2)
    CMK(13, S1, sg * C1)  CMK(14, -R2, sg * R2)  CMK(15, -C1, -sg * S1)
#undef CMK
#pragma unroll
    for (int j = 0; j < 4; ++j) {
        float ar = tr[4 * j],     ai = ti[4 * j];
        float br = tr[4 * j + 1], bi = ti[4 * j + 1];
        float cr = tr[4 * j + 2], ci = ti[4 * j + 2];
        float dr = tr[4 * j + 3], di = ti[4 * j + 3];
        float t0r = ar + cr, t0i = ai + ci;
        float t1r = ar - cr, t1i = ai - ci;
        float t2r = br + dr, t2i = bi + di;
        float t3r = br - dr, t3i = bi - di;
        xr[j]      = t0r + t2r; xi[j]      = t0i + t2i;
        xr[8 + j]  = t0r - t2r; xi[8 + j]  = t0i - t2i;
        if constexpr (!INV) {
            xr[4 + j]  = t1r + t3i; xi[4 + j]  = t1i - t3r;
            xr[12 + j] = t1r - t3i; xi[12 + j] = t1i + t3r;
        } else {
            xr[4 + j]  = t1r - t3i; xi[4 + j]  = t1i + t3r;
            xr[12 + j] = t1r + t3i; xi[12 + j] = t1i - t3r;
        }
    }
}

#define CMUL_ADV(wr, wi, sr, si) { float _n = (wr)*(sr) - (wi)*(si); \
        (wi) = (wr)*(si) + (wi)*(sr); (wr) = _n; }

// fused RPE projection + forward FFT -> af (chi order)
__global__ __launch_bounds__(256, 3) void fft_a_kernel(
    const float* __restrict__ hgT, const float* __restrict__ ow,
    const float* __restrict__ ob, float2* __restrict__ af) {
    __shared__ float2 buf[4608];
    int tid = threadIdx.x;
    int col = blockIdx.x;
    float2* orow = af + ((size_t)col << 12);
    float xr[16], xi[16];
    float bsr, bsi, wr, wi;
    float obc = ob[col];
#pragma unroll
    for (int a = 0; a < 16; ++a) { xr[a] = obc; xi[a] = 0.f; }
    for (int k = 0; k < 32; ++k) {
        float wk = ow[k * D1C + col];
        const float* hrow = hgT + (k << 12) + tid;
#pragma unroll
        for (int a = 0; a < 16; ++a) xr[a] = fmaf(hrow[a * 256], wk, xr[a]);
    }
    dft16<false, false>(xr, xi);
    __sincosf(-(float)M_PI / 2048.f * (float)tid, &bsi, &bsr);
    wr = bsr; wi = bsi;
    buf[LIDX(tid)] = make_float2(xr[0], xi[0]);
#pragma unroll
    for (int k0 = 1; k0 < 16; ++k0) {
        buf[LIDX(k0 * 256 + tid)] =
            make_float2(xr[k0] * wr - xi[k0] * wi, xr[k0] * wi + xi[k0] * wr);
        CMUL_ADV(wr, wi, bsr, bsi);
    }
    __syncthreads();
    int k0 = tid >> 4, cc = tid & 15;
    int base2 = k0 * 256 + cc;
#pragma unroll
    for (int b = 0; b < 16; ++b) {
        float2 v = buf[LIDX(base2 + b * 16)]; xr[b] = v.x; xi[b] = v.y;
    }
    dft16<false, false>(xr, xi);
    __sincosf(-(float)M_PI / 128.f * (float)cc, &bsi, &bsr);
    wr = bsr; wi = bsi;
    buf[LIDX(base2)] = make_float2(xr[0], xi[0]);
#pragma unroll
    for (int k1 = 1; k1 < 16; ++k1) {
        buf[LIDX(base2 + k1 * 16)] =
            make_float2(xr[k1] * wr - xi[k1] * wi, xr[k1] * wi + xi[k1] * wr);
        CMUL_ADV(wr, wi, bsr, bsi);
    }
    __syncthreads();
    const float4* pld = (const float4*)&buf[18 * tid];
#pragma unroll
    for (int h = 0; h < 8; ++h) {
        float4 q = pld[h];
        xr[2 * h] = q.x; xi[2 * h] = q.y; xr[2 * h + 1] = q.z; xi[2 * h + 1] = q.w;
    }
    dft16<false, false>(xr, xi);
#pragma unroll
    for (int k2 = 0; k2 < 16; ++k2)
        orow[k2 * 256 + tid] = make_float2(xr[k2], xi[k2]);
}

// packed circular convolution: z = v[b0] + i*v[b1]; fwd FFT -> *af -> inv FFT
__global__ __launch_bounds__(256, 3) void conv_kernel(float* __restrict__ vt,
                                                      const float2* __restrict__ af) {
    __shared__ float2 buf[4608];
    int tid = threadIdx.x;
    int pr  = blockIdx.x / D1C;
    int col = blockIdx.x % D1C;
    float* v0 = vt + ((size_t)((2 * pr)     * D1C + col) << 11);
    float* v1 = vt + ((size_t)((2 * pr + 1) * D1C + col) << 11);
    const float2* arow = af + ((size_t)col << 12);
    float xr[16], xi[16];
    float bsr, bsi, wr, wi;

#pragma unroll
    for (int a = 0; a < 8; ++a) { xr[a] = v0[a * 256 + tid]; xi[a] = v1[a * 256 + tid]; }
    dft16<false, true>(xr, xi);
    __sincosf(-(float)M_PI / 2048.f * (float)tid, &bsi, &bsr);
    wr = bsr; wi = bsi;
    buf[LIDX(tid)] = make_float2(xr[0], xi[0]);
#pragma unroll
    for (int k0 = 1; k0 < 16; ++k0) {
        buf[LIDX(k0 * 256 + tid)] =
            make_float2(xr[k0] * wr - xi[k0] * wi, xr[k0] * wi + xi[k0] * wr);
        CMUL_ADV(wr, wi, bsr, bsi);
    }
    __syncthreads();
    int k0 = tid >> 4, cc = tid & 15;
    int base2 = k0 * 256 + cc;
#pragma unroll
    for (int b = 0; b < 16; ++b) {
        float2 v = buf[LIDX(base2 + b * 16)]; xr[b] = v.x; xi[b] = v.y;
    }
    dft16<false, false>(xr, xi);
    __sincosf(-(float)M_PI / 128.f * (float)cc, &bsi, &bsr);
    wr = bsr; wi = bsi;
    buf[LIDX(base2)] = make_float2(xr[0], xi[0]);
#pragma unroll
    for (int k1 = 1; k1 < 16; ++k1) {
        buf[LIDX(base2 + k1 * 16)] =
            make_float2(xr[k1] * wr - xi[k1] * wi, xr[k1] * wi + xi[k1] * wr);
        CMUL_ADV(wr, wi, bsr, bsi);
    }
    __syncthreads();
    const float4* pld = (const float4*)&buf[18 * tid];
#pragma unroll
    for (int h = 0; h < 8; ++h) {
        float4 q = pld[h];
        xr[2 * h] = q.x; xi[2 * h] = q.y; xr[2 * h + 1] = q.z; xi[2 * h + 1] = q.w;
    }
    dft16<false, false>(xr, xi);
    const float inv = 1.0f / 4096.0f;
#pragma unroll
    for (int k2 = 0; k2 < 16; ++k2) {
        float2 w = arow[k2 * 256 + tid];
        float rr = (xr[k2] * w.x - xi[k2] * w.y) * inv;
        float ii = (xr[k2] * w.y + xi[k2] * w.x) * inv;
        xr[k2] = rr; xi[k2] = ii;
    }
    dft16<true, false>(xr, xi);
    __sincosf((float)M_PI / 128.f * (float)cc, &bsi, &bsr);
    wr = bsr; wi = bsi;
#pragma unroll
    for (int c = 1; c < 16; ++c) {
        float rr = xr[c] * wr - xi[c] * wi;
        xi[c] = xr[c] * wi + xi[c] * wr; xr[c] = rr;
        CMUL_ADV(wr, wi, bsr, bsi);
    }
    float4* pst = (float4*)&buf[18 * tid];
#pragma unroll
    for (int h = 0; h < 8; ++h)
        pst[h] = make_float4(xr[2 * h], xi[2 * h], xr[2 * h + 1], xi[2 * h + 1]);
    __syncthreads();
#pragma unroll
    for (int k1 = 0; k1 < 16; ++k1) {
        float2 v = buf[LIDX(base2 + k1 * 16)]; xr[k1] = v.x; xi[k1] = v.y;
    }
    dft16<true, false>(xr, xi);
    float swr, swi;
    __sincosf((float)M_PI / 2048.f * (float)(k0 * cc), &bsi, &bsr);
    __sincosf((float)M_PI / 128.f * (float)k0, &swi, &swr);
    wr = bsr; wi = bsi;
#pragma unroll
    for (int b = 0; b < 16; ++b) {
        buf[LIDX(base2 + b * 16)] =
            make_float2(xr[b] * wr - xi[b] * wi, xr[b] * wi + xi[b] * wr);
        CMUL_ADV(wr, wi, swr, swi);
    }
    __syncthreads();
#pragma unroll
    for (int k = 0; k < 16; ++k) {
        float2 v = buf[LIDX(k * 256 + tid)]; xr[k] = v.x; xi[k] = v.y;
    }
    dft16<true, false>(xr, xi);
#pragma unroll
    for (int a = 0; a < 8; ++a) {
        v0[a * 256 + tid] = xr[a];
        v1[a * 256 + tid] = xi[a];
    }
}

// ---------------------------------------------------------------------------
// MFMA 2-pass split-f16 GEMM: C = (Ah+Al)*Bh, fp32 accum.
// 3-buffer LDS ring, prefetch distance 2, counted vmcnt + raw s_barrier:
// the prefetch for tile t+2 stays in flight across the barrier (never
// vmcnt(0) in the main loop) — removes the m97-style barrier-drain stall.
enum { EP_SILU_F32, EP_SILU_VT, EP_PLAIN, EP_GLU2 };

template <int BM, int K, int EPI>
__global__ __launch_bounds__(256, (BM == 128 ? 2 : 3)) void mgemm(
    const f16* __restrict__ Ah, const f16* __restrict__ Al,
    const f16* __restrict__ Bh,
    const float* __restrict__ bias, const float* __restrict__ E0,
    float* __restrict__ OutF, f16* __restrict__ OutH, f16* __restrict__ OutL,
    int Ncols) {
    constexpr int SB   = BM * 128 + 8192;        // bytes per K-tile buffer
    constexpr int MREP = BM / 32;
    constexpr int LOGB = (BM == 128 ? 7 : 6);
    constexpr int CA   = BM / 64;
    constexpr int LPT  = CA * 2 + 2;             // loads/thread/stage (6 or 4)
    __shared__ __align__(16) char smem[3 * SB];

    const int tid  = threadIdx.x;
    const int w    = tid >> 6, lane = tid & 63;
    const int wr   = w >> 1, wc = w & 1;
    const int l15  = lane & 15, kc = lane >> 4;

    const int NBY = Ncols >> 7;
    const int nwg = gridDim.x;
    int flat = blockIdx.x;
    int q8 = nwg >> 3, r8 = nwg & 7;
    int xcd = flat & 7, pos = flat >> 3;
    int wg = (xcd < r8 ? xcd * (q8 + 1) : r8 * (q8 + 1) + (xcd - r8) * q8) + pos;
    const int row0 = (wg / NBY) * BM;
    const int col0 = (wg % NBY) * 128;

    f32x4 acc[MREP][4] = {};

    auto stage = [&](int buf, int kt) {
        const int k0 = kt * 32;
        const int bb = buf * SB;
#pragma unroll
        for (int l = 0; l < CA; ++l) {
            int ci = tid + l * 256;
            int r = ci & (BM - 1), kk = ci >> LOGB;
            const f16* ga = Ah + (size_t)(row0 + r) * K + k0 + kk * 8;
            const f16* gb = Al + (size_t)(row0 + r) * K + k0 + kk * 8;
            __builtin_amdgcn_global_load_lds((const __attribute__((address_space(1))) u32*)ga,
                (__attribute__((address_space(3))) u32*)(smem + bb + ci * 16), 16, 0, 0);
            __builtin_amdgcn_global_load_lds((const __attribute__((address_space(1))) u32*)gb,
                (__attribute__((address_space(3))) u32*)(smem + bb + BM * 64 + ci * 16), 16, 0, 0);
        }
#pragma unroll
        for (int l = 0; l < 2; ++l) {
            int ci = tid + l * 256;
            int c = ci & 127, kk = ci >> 7;
            const f16* gc = Bh + (size_t)(col0 + c) * K + k0 + kk * 8;
            __builtin_amdgcn_global_load_lds((const __attribute__((address_space(1))) u32*)gc,
                (__attribute__((address_space(3))) u32*)(smem + bb + BM * 128 + ci * 16), 16, 0, 0);
        }
    };

    auto compute = [&](int buf) {
        const char* base = smem + buf * SB;
        f16x8 a_h[MREP], a_l[MREP], b_h[4];
#pragma unroll
        for (int m = 0; m < MREP; ++m) {
            int r = wr * (BM / 2) + m * 16 + l15;
            a_h[m] = *(const f16x8*)(base + (kc * BM + r) * 16);
            a_l[m] = *(const f16x8*)(base + BM * 64 + (kc * BM + r) * 16);
        }
#pragma unroll
        for (int n = 0; n < 4; ++n) {
            int c = wc * 64 + n * 16 + l15;
            b_h[n] = *(const f16x8*)(base + BM * 128 + (kc * 128 + c) * 16);
        }
#pragma unroll
        for (int m = 0; m < MREP; ++m)
#pragma unroll
            for (int n = 0; n < 4; ++n) {
                acc[m][n] = __builtin_amdgcn_mfma_f32_16x16x32_f16(a_h[m], b_h[n], acc[m][n], 0, 0, 0);
                acc[m][n] = __builtin_amdgcn_mfma_f32_16x16x32_f16(a_l[m], b_h[n], acc[m][n], 0, 0, 0);
            }
    };

    constexpr int NT = K / 32;
    // prologue: fill pipeline to depth 2
    stage(0, 0);
    stage(1, 1);
    asm volatile("s_waitcnt vmcnt(%0)" :: "i"(LPT) : "memory");  // tile0 landed
    __builtin_amdgcn_s_barrier();
    asm volatile("" ::: "memory");

    int cc_ = 0, cs_ = 2;
    for (int t = 0; t < NT; ++t) {
        if (t + 2 < NT) { stage(cs_, t + 2); cs_ = (cs_ == 2) ? 0 : cs_ + 1; }
        compute(cc_); cc_ = (cc_ == 2) ? 0 : cc_ + 1;
        if (t + 2 < NT) {
            // wait for tile t+1 only; tile t+2's loads stay in flight
            asm volatile("s_waitcnt vmcnt(%0)" :: "i"(LPT) : "memory");
            __builtin_amdgcn_s_barrier();
            asm volatile("" ::: "memory");
        } else if (t + 1 < NT) {
            asm volatile("s_waitcnt vmcnt(0)" ::: "memory");
            __builtin_amdgcn_s_barrier();
            asm volatile("" ::: "memory");
        }
    }

    const int WRB = wr * (BM / 2);
    if constexpr (EPI == EP_SILU_VT) {
        float* patch = (float*)(smem + w * 5376);        // [64][20] f32, padded
#pragma unroll
        for (int m = 0; m < MREP; ++m) {
            __syncthreads();
#pragma unroll
            for (int n = 0; n < 4; ++n)
#pragma unroll
                for (int r = 0; r < 4; ++r)
                    patch[(n * 16 + l15) * 20 + kc * 4 + r] = acc[m][n][r];
            __syncthreads();
#pragma unroll
            for (int t = 0; t < 4; ++t) {
                int qi = lane + t * 64;
                int col_ = qi >> 2, rq = qi & 3;
                float4 y = *(const float4*)&patch[col_ * 20 + rq * 4];
                int col = col0 + wc * 64 + col_;
                float bb = bias[col];
                y.x = silu_f(y.x + bb); y.y = silu_f(y.y + bb);
                y.z = silu_f(y.z + bb); y.w = silu_f(y.w + bb);
                int b = row0 >> 11;
                int seq = (row0 & 2047) + WRB + m * 16 + rq * 4;
                *(float4*)&OutF[(((size_t)(b * D1C + col)) << 11) + seq] = y;
            }
        }
    } else {
        float* patch = (float*)(smem + w * 4352);        // [16][68] f32, padded
#pragma unroll
        for (int m = 0; m < MREP; ++m) {
            __syncthreads();
#pragma unroll
            for (int n = 0; n < 4; ++n)
#pragma unroll
                for (int r = 0; r < 4; ++r)
                    patch[(kc * 4 + r) * 68 + n * 16 + l15] = acc[m][n][r];
            __syncthreads();
#pragma unroll
            for (int t = 0; t < 4; ++t) {
                int qi = lane + t * 64;
                int row_ = qi >> 4, q = qi & 15;
                float4 y = *(const float4*)&patch[row_ * 68 + q * 4];
                int row = row0 + WRB + m * 16 + row_;
                int col = col0 + wc * 64 + q * 4;
                float4 bb = *(const float4*)&bias[col];
                y.x += bb.x; y.y += bb.y; y.z += bb.z; y.w += bb.w;
                size_t idx = (size_t)row * Ncols + col;
                if constexpr (EPI == EP_SILU_F32) {
                    y.x = silu_f(y.x); y.y = silu_f(y.y);
                    y.z = silu_f(y.z); y.w = silu_f(y.w);
                    *(float4*)&OutF[idx] = y;
                } else if constexpr (EPI == EP_PLAIN) {
                    *(float4*)&OutF[idx] = y;
                } else {  // EP_GLU2
                    float4 e = *(const float4*)&E0[idx];
                    float z0 = e.x * y.x, z1 = e.y * y.y, z2 = e.z * y.z, z3 = e.w * y.w;
                    f16x4 h, l;
                    h[0] = (f16)z0; l[0] = (f16)(z0 - (float)h[0]);
                    h[1] = (f16)z1; l[1] = (f16)(z1 - (float)h[1]);
                    h[2] = (f16)z2; l[2] = (f16)(z2 - (float)h[2]);
                    h[3] = (f16)z3; l[3] = (f16)(z3 - (float)h[3]);
                    *(f16x4*)&OutH[idx] = h;
                    *(f16x4*)&OutL[idx] = l;
                }
            }
        }
    }
}

// ---------------------------------------------------------------------------
extern "C" void kernel_launch(void* const* d_in, const int* in_sizes, int n_in,
                              void* d_out, int out_size, void* d_ws, size_t ws_size,
                              hipStream_t stream) {
    const float* x   = (const float*)d_in[1];
    const float* u_w = (const float*)d_in[2];
    const float* u_b = (const float*)d_in[3];
    const float* v_w = (const float*)d_in[4];
    const float* v_b = (const float*)d_in[5];
    const float* o_w = (const float*)d_in[6];
    const float* o_b = (const float*)d_in[7];
    const float* rpw = (const float*)d_in[8];
    const float* rpb = (const float*)d_in[9];
    const float* rlw = (const float*)d_in[10];
    const float* rlb = (const float*)d_in[11];
    const float* row_w = (const float*)d_in[12];
    const float* rob = (const float*)d_in[13];
    const float* g1w = (const float*)d_in[14];
    const float* g1b = (const float*)d_in[15];
    const float* g2w = (const float*)d_in[16];
    const float* g2b = (const float*)d_in[17];
    const float* g3w = (const float*)d_in[18];
    const float* g3b = (const float*)d_in[19];

    char* wsb = (char*)d_ws;
    float* scale = (float*)wsb;                       // 64 KB slot
    char* R1 = wsb + (1 << 16);                       // af spectrum, later ph+pl
    char* R2 = R1 + 50331648;                         // vt, later tmp1
    char* R3 = R2 + 50331648;                         // hgT, then u, later zh+zl
    char* R4 = R3 + 50331648;                         // xn hi/lo, later x2 hi/lo
    char* R5 = R4 + 16777216;                         // 6 transposed f16 weights

    float2* af   = (float2*)R1;
    f16*    ph   = (f16*)R1;
    f16*    pl   = (f16*)(R1 + 25165824);
    float*  vt   = (float*)R2;
    float*  tmp1 = (float*)R2;
    float*  hgT  = (float*)R3;
    float*  u    = (float*)R3;
    f16*    zh   = (f16*)R3;
    f16*    zl   = (f16*)(R3 + 25165824);
    f16*    xnh  = (f16*)R4;
    f16*    xnl  = (f16*)(R4 + 8388608);
    f16*    x2h  = xnh;
    f16*    x2l  = xnl;

    auto wTh = [&](int i) { return (f16*)(R5 + (size_t)i * 1572864); };

    float* g_out   = (float*)d_out;
    float* out_out = g_out + (size_t)BATCH * NSEQ * EMBC;

    // prologue
    scale_kernel<<<2048, 256, 0, stream>>>(x, scale);
    convert_xn_kernel<<<4096, 256, 0, stream>>>(x, scale, xnh, xnl);
    wtrans_kernel<<<dim3(48, 16), 256, 0, stream>>>(u_w, wTh(0), 512, 1536);
    wtrans_kernel<<<dim3(48, 16), 256, 0, stream>>>(v_w, wTh(1), 512, 1536);
    wtrans_kernel<<<dim3(16, 48), 256, 0, stream>>>(o_w, wTh(2), 1536, 512);
    wtrans_kernel<<<dim3(48, 16), 256, 0, stream>>>(g1w, wTh(3), 512, 1536);
    wtrans_kernel<<<dim3(48, 16), 256, 0, stream>>>(g2w, wTh(4), 512, 1536);
    wtrans_kernel<<<dim3(16, 48), 256, 0, stream>>>(g3w, wTh(5), 1536, 512);
    rpe_mlp_kernel<<<16, 256, 0, stream>>>(rpw, rpb, rlw, rlb, hgT);
    fft_a_kernel<<<1536, 256, 0, stream>>>(hgT, row_w, rob, af);

    // u, v projections (M=8192, N=1536, K=512)
    mgemm<128, 512, EP_SILU_F32><<<768, 256, 0, stream>>>(
        xnh, xnl, wTh(0), u_b, nullptr, u, nullptr, nullptr, 1536);
    mgemm<128, 512, EP_SILU_VT><<<768, 256, 0, stream>>>(
        xnh, xnl, wTh(1), v_b, nullptr, vt, nullptr, nullptr, 1536);

    // Toeplitz via packed FFT conv, then p = u * t -> f16 split
    conv_kernel<<<3072, 256, 0, stream>>>(vt, af);
    convert_p_kernel<<<dim3(64, 48, 4), 256, 0, stream>>>(u, vt, ph, pl);

    // out = p @ o_w + o_b  (N=512, K=1536)
    mgemm<64, 1536, EP_PLAIN><<<512, 256, 0, stream>>>(
        ph, pl, wTh(2), o_b, nullptr, out_out, nullptr, nullptr, 512);

    // GLU
    convert_x2_kernel<<<4096, 256, 0, stream>>>(out_out, x, x2h, x2l);
    mgemm<128, 512, EP_SILU_F32><<<768, 256, 0, stream>>>(
        x2h, x2l, wTh(3), g1b, nullptr, tmp1, nullptr, nullptr, 1536);
    mgemm<128, 512, EP_GLU2><<<768, 256, 0, stream>>>(
        x2h, x2l, wTh(4), g2b, tmp1, nullptr, zh, zl, 1536);
    mgemm<64, 1536, EP_PLAIN><<<512, 256, 0, stream>>>(
        zh, zl, wTh(5), g3b, nullptr, g_out, nullptr, nullptr, 512);
}